// Round 8
// baseline (439.360 us; speedup 1.0000x reference)
//
#include <hip/hip_runtime.h>

// B=8, L=2048, D=512, H=512, E=256, K=30.  fp32 I/O, x_lengths int32.
// Identity: softmax -> key-mask -> renorm -> top-30 -> renorm ==
//   softmax over the 30 largest raw logits among valid keys (len >= 1024 >> 30).
// GEMMs (k1,k3): f16 MFMA.  Scores: v_dot2_f32_f16, key-split across waves,
// u-packed (21-bit score + 11-bit reverse index) into an LDS score matrix;
// per-row top-30 extraction by value-only wave-max.

typedef _Float16 h2   __attribute__((ext_vector_type(2)));
typedef _Float16 h4   __attribute__((ext_vector_type(4)));
typedef _Float16 h8   __attribute__((ext_vector_type(8)));
typedef float    f32x4 __attribute__((ext_vector_type(4)));

__device__ __forceinline__ h2 as_h2(float f) {
    union { float f; h2 h; } u; u.f = f; return u.h;
}
__device__ __forceinline__ float packh2(float a, float b) {
    union { h2 h; float f; } u; u.h.x = (_Float16)a; u.h.y = (_Float16)b; return u.f;
}

// ---------------------------------------------------------------------------
// k0: transpose-pack fp32 [K][N] -> f16 [N][K].  32x32 tiles.
// ---------------------------------------------------------------------------
__global__ __launch_bounds__(256) void k0_tp(
    const float* __restrict__ src, _Float16* __restrict__ dst, int Kd, int Nd)
{
    __shared__ float tile[32][33];
    const int t = threadIdx.x;
    const int n0 = blockIdx.x * 32, k0 = blockIdx.y * 32;
    const int r = t >> 3, c = (t & 7) * 4;
    *(float4*)&tile[r][c] = *(const float4*)(src + (size_t)(k0 + r) * Nd + n0 + c);
    __syncthreads();
    h4 hv;
    hv.x = (_Float16)tile[c + 0][r];
    hv.y = (_Float16)tile[c + 1][r];
    hv.z = (_Float16)tile[c + 2][r];
    hv.w = (_Float16)tile[c + 3][r];
    *(h4*)(dst + (size_t)(n0 + r) * Kd + k0 + c) = hv;
}

// ---------------------------------------------------------------------------
// k1: MFMA projection GEMM.  BM=64 rows x BN=256 cols, BK=64, 4 waves.
// blockIdx.y = col-block: 0,1 -> x_prime (h2-packed xph), 2 -> x1 (x1p),
// 3 -> x2 (transposed packed x2tp via LDS tile).
// ---------------------------------------------------------------------------
__global__ __launch_bounds__(256) void k1_mfma(
    const float* __restrict__ x, const _Float16* __restrict__ wT,
    const float* __restrict__ bg, const float* __restrict__ b1,
    const float* __restrict__ b2,
    float* __restrict__ xph, float* __restrict__ x1p, float* __restrict__ x2tp)
{
    __shared__ __align__(16) char lds_raw[40960];
    _Float16* Alds = (_Float16*)lds_raw;             // [64][64] f16 = 8 KB
    _Float16* Blds = (_Float16*)(lds_raw + 8192);    // [256][64] f16 = 32 KB

    const int t = threadIdx.x;
    const int m0 = blockIdx.x * 64;
    const int cb = blockIdx.y;
    const int n0 = cb * 256;                         // row base in wT
    const int lane = t & 63, w = t >> 6;
    const int arow = lane & 15, ak = (lane >> 4) * 8;

    f32x4 acc[4][4];
    #pragma unroll
    for (int i = 0; i < 4; ++i)
        #pragma unroll
        for (int j = 0; j < 4; ++j) acc[i][j] = (f32x4){0.f, 0.f, 0.f, 0.f};

    for (int k0 = 0; k0 < 512; k0 += 64) {
        __syncthreads();
        {   // stage A: 64 rows x 64 k fp32 -> f16
            const int r = t >> 2, c0 = (t & 3) * 16;
            const float* src = x + (size_t)(m0 + r) * 512 + k0 + c0;
            #pragma unroll
            for (int hvi = 0; hvi < 2; ++hvi) {
                float4 u0 = *(const float4*)(src + hvi * 8);
                float4 u1 = *(const float4*)(src + hvi * 8 + 4);
                h8 hv;
                hv[0] = (_Float16)u0.x; hv[1] = (_Float16)u0.y;
                hv[2] = (_Float16)u0.z; hv[3] = (_Float16)u0.w;
                hv[4] = (_Float16)u1.x; hv[5] = (_Float16)u1.y;
                hv[6] = (_Float16)u1.z; hv[7] = (_Float16)u1.w;
                *(h8*)(Alds + r * 64 + c0 + hvi * 8) = hv;
            }
        }
        {   // stage B: 256 n-rows x 64 k f16.  8 lanes cover one 128B row.
            #pragma unroll
            for (int i = 0; i < 8; ++i) {
                int idx = t + i * 256;               // 0..2047
                int row = idx >> 3, ch = idx & 7;
                *(float4*)(Blds + row * 64 + ch * 8) =
                    *(const float4*)(wT + (size_t)(n0 + row) * 512 + k0 + ch * 8);
            }
        }
        __syncthreads();

        #pragma unroll
        for (int kk = 0; kk < 2; ++kk) {
            h8 af[4], bf[4];
            #pragma unroll
            for (int rb = 0; rb < 4; ++rb)
                af[rb] = *(const h8*)(Alds + (rb * 16 + arow) * 64 + kk * 32 + ak);
            #pragma unroll
            for (int cf = 0; cf < 4; ++cf)
                bf[cf] = *(const h8*)(Blds + (w * 64 + cf * 16 + arow) * 64 + kk * 32 + ak);
            #pragma unroll
            for (int rb = 0; rb < 4; ++rb)
                #pragma unroll
                for (int cf = 0; cf < 4; ++cf)
                    acc[rb][cf] = __builtin_amdgcn_mfma_f32_16x16x32_f16(
                        af[rb], bf[cf], acc[rb][cf], 0, 0, 0);
        }
    }

    const float* bias = (cb < 2) ? (bg + cb * 256) : (cb == 2 ? b1 : b2);

    if (cb < 3) {
        // pack e-pairs via lane shuffle; even lanes store 4B
        float* dst; int epbase; size_t rstr;
        if (cb < 2) { dst = xph; epbase = cb * 128; rstr = 256; }
        else        { dst = x1p; epbase = 0;        rstr = 128; }
        #pragma unroll
        for (int cf = 0; cf < 4; ++cf) {
            const int c = w * 64 + cf * 16 + arow;
            const float bv = bias[c];
            #pragma unroll
            for (int rb = 0; rb < 4; ++rb) {
                #pragma unroll
                for (int j = 0; j < 4; ++j) {
                    float v = acc[rb][cf][j] + bv;
                    float o = __shfl_xor(v, 1);
                    if ((lane & 1) == 0) {
                        int row = m0 + rb * 16 + (lane >> 4) * 4 + j;
                        dst[(size_t)row * rstr + epbase + (c >> 1)] = packh2(v, o);
                    }
                }
            }
        }
    } else {
        // x2: pack pairs -> LDS tile T[ep][key] (stride 68) -> coalesced store
        __syncthreads();                              // done with Alds/Blds
        float* T = (float*)lds_raw;                   // [128][68] floats = 34816 B
        #pragma unroll
        for (int cf = 0; cf < 4; ++cf) {
            const int c = w * 64 + cf * 16 + arow;
            const float bv = bias[c];
            #pragma unroll
            for (int rb = 0; rb < 4; ++rb) {
                #pragma unroll
                for (int j = 0; j < 4; ++j) {
                    float v = acc[rb][cf][j] + bv;
                    float o = __shfl_xor(v, 1);
                    if ((lane & 1) == 0)
                        T[(c >> 1) * 68 + rb * 16 + (lane >> 4) * 4 + j] = packh2(v, o);
                }
            }
        }
        __syncthreads();
        const int bb = m0 >> 11, j0 = m0 & 2047;
        #pragma unroll
        for (int g = 0; g < 8; ++g) {
            int idx4 = t + g * 256;                   // 0..2047
            int ep = idx4 >> 4, ko = (idx4 & 15) * 4;
            float4 vv = *(const float4*)(T + ep * 68 + ko);
            *(float4*)(x2tp + ((size_t)bb * 128 + ep) * 2048 + j0 + ko) = vv;
        }
    }
}

// ---------------------------------------------------------------------------
// k2: 256 threads (4 waves), 8 query rows per block.
// Phase A (key-split): wave w scores all 8 rows x keys [w*512, w*512+512);
//   lane owns keys {kb0..kb0+3, kb0+256..kb0+259}; each x2tp float4 load
//   feeds 8 rows -> block reads the 1 MB panel ONCE (was 8x).
//   Scores u-packed (21-bit score | 11-bit (2047-j)) -> LDS scU[8][2048].
// Phase B (row-split): wave w extracts top-30 of rows {2w,2w+1} from scU
//   by value-only wave-max (identical to proven round-7 macro).
// Phase C: unpack, shared softmax weights, h2-packed gather of x_prime.
// ---------------------------------------------------------------------------
__global__ __launch_bounds__(256, 2) void k2_attn(
    const float* __restrict__ x1p, const float* __restrict__ x2tp,
    const float* __restrict__ xph, const int* __restrict__ xlen,
    float* __restrict__ yah)
{
    __shared__ unsigned scU[8][2048];             // 64 KB score matrix
    __shared__ float    x1sT[128][8];             // 4 KB  x1 transposed (h2 pairs)
    __shared__ unsigned tkp[8][30];
    __shared__ float    wvs[8][30];
    __shared__ int      tki[8][30];
    __shared__ float    vin[8];

    const int t  = threadIdx.x;
    const int b  = blockIdx.x >> 8;               // 256 row-blocks per batch
    const int i0 = (blockIdx.x & 255) * 8;
    const int len = xlen[b];

    {   // stage x1 (8 rows x 128 ep-pairs) transposed into LDS
        const float* x1b = x1p + ((size_t)b * 2048 + i0) * 128;
        const int f = t * 4;                      // 0..1023
        const int row = f >> 7, ep = f & 127;
        float4 v = *(const float4*)(x1b + f);
        x1sT[ep + 0][row] = v.x; x1sT[ep + 1][row] = v.y;
        x1sT[ep + 2][row] = v.z; x1sT[ep + 3][row] = v.w;
    }
    __syncthreads();

    const int lane = t & 63, wid = t >> 6;        // 4 waves
    const int kb0 = wid * 512 + lane * 4;         // keys kb0..+3 and kb0+256..+259

    // ---- phase A: scores, 8 rows x 8 keys per lane ----
    float acc[8][8];
    #pragma unroll
    for (int r = 0; r < 8; ++r)
        #pragma unroll
        for (int kk = 0; kk < 8; ++kk) acc[r][kk] = 0.f;

    const float* x2tb = x2tp + (size_t)b * 128 * 2048;
    for (int ep = 0; ep < 128; ++ep) {
        const float* rowp = x2tb + (size_t)ep * 2048;
        float4 kv0 = *(const float4*)(rowp + kb0);
        float4 kv1 = *(const float4*)(rowp + kb0 + 256);
        float4 xa = *(const float4*)&x1sT[ep][0];
        float4 xb = *(const float4*)&x1sT[ep][4];
        const h2 xr[8] = { as_h2(xa.x), as_h2(xa.y), as_h2(xa.z), as_h2(xa.w),
                           as_h2(xb.x), as_h2(xb.y), as_h2(xb.z), as_h2(xb.w) };
        const h2 kh[8] = { as_h2(kv0.x), as_h2(kv0.y), as_h2(kv0.z), as_h2(kv0.w),
                           as_h2(kv1.x), as_h2(kv1.y), as_h2(kv1.z), as_h2(kv1.w) };
        #pragma unroll
        for (int r = 0; r < 8; ++r)
            #pragma unroll
            for (int kk = 0; kk < 8; ++kk)
                acc[r][kk] = __builtin_amdgcn_fdot2(xr[r], kh[kk], acc[r][kk], false);
    }

    // ---- u-pack + store to LDS score matrix (16B/lane stride: no conflicts) ----
    #pragma unroll
    for (int r = 0; r < 8; ++r) {
        unsigned uu[8];
        #pragma unroll
        for (int kk = 0; kk < 8; ++kk) {
            const int j = kb0 + (kk & 3) + (kk >= 4 ? 256 : 0);
            const unsigned tag = (unsigned)(2047 - j);
            unsigned bb = __float_as_uint(acc[r][kk]);
            bb = bb ^ (0x80000000u | (unsigned)((int)bb >> 31));
            uu[kk] = (j < len) ? ((bb & 0xFFFFF800u) | tag) : 0u;
        }
        *(uint4*)&scU[r][kb0]       = make_uint4(uu[0], uu[1], uu[2], uu[3]);
        *(uint4*)&scU[r][kb0 + 256] = make_uint4(uu[4], uu[5], uu[6], uu[7]);
    }
    __syncthreads();

    // ---- phase B: top-30 per row; wave w owns rows {2w, 2w+1} ----
    const int r0 = wid * 2;
    const int cbase = lane * 4;
    unsigned u0[32], u1[32];
    #pragma unroll
    for (int c = 0; c < 8; ++c) {
        *(uint4*)&u0[c * 4] = *(const uint4*)&scU[r0][cbase + c * 256];
        *(uint4*)&u1[c * 4] = *(const uint4*)&scU[r0 + 1][cbase + c * 256];
    }

#define TOPK_ROW(U, ROW)                                                    \
    for (int it = 0; it < 30; ++it) {                                       \
        unsigned mx = 0u;                                                   \
        _Pragma("unroll")                                                   \
        for (int q = 0; q < 32; ++q) mx = mx > U[q] ? mx : U[q];            \
        _Pragma("unroll")                                                   \
        for (int off = 32; off > 0; off >>= 1) {                            \
            unsigned o = (unsigned)__shfl_xor((int)mx, off);                \
            mx = mx > o ? mx : o;                                           \
        }                                                                   \
        if (lane == 0) tkp[ROW][it] = mx;                                   \
        _Pragma("unroll")                                                   \
        for (int q = 0; q < 32; ++q) U[q] = (U[q] == mx) ? 0u : U[q];       \
    }

    TOPK_ROW(u0, r0)
    TOPK_ROW(u1, r0 + 1)
#undef TOPK_ROW
    __syncthreads();

    // ---- unpack + per-row softmax weights ----
    {
        const int r = t >> 5, k = t & 31;
        if (k < 30) {
            unsigned u = tkp[r][k];
            unsigned m0 = tkp[r][0] & 0xFFFFF800u;
            unsigned ub = u & 0xFFFFF800u;
            unsigned bb0 = (m0 & 0x80000000u) ? (m0 ^ 0x80000000u) : ~m0;
            unsigned bbk = (ub & 0x80000000u) ? (ub ^ 0x80000000u) : ~ub;
            float s0 = __uint_as_float(bb0);
            float sk = __uint_as_float(bbk);
            wvs[r][k] = __expf(sk - s0);
            tki[r][k] = 2047 - (int)(u & 0x7FFu);
        }
    }
    __syncthreads();
    if (t < 8) {
        float s = 0.f;
        #pragma unroll
        for (int k = 0; k < 30; ++k) s += wvs[t][k];
        vin[t] = 1.f / s;
    }
    __syncthreads();

    // ---- phase C: gather of h2-packed x_prime with shared weights ----
    const int hp = t;                             // h2-pair index 0..255
    for (int r = 0; r < 8; ++r) {
        float y0 = 0.f, y1 = 0.f;
        #pragma unroll
        for (int k = 0; k < 30; ++k) {
            int j = tki[r][k];
            float wv = wvs[r][k];
            h2 u = as_h2(xph[((size_t)b * 2048 + j) * 256 + hp]);
            y0 = fmaf(wv, (float)u.x, y0);
            y1 = fmaf(wv, (float)u.y, y1);
        }
        const float inv = vin[r];
        yah[((size_t)b * 2048 + i0 + r) * 256 + hp] = packh2(y0 * inv, y1 * inv);
    }
}

// ---------------------------------------------------------------------------
// k3: out = x + yah @ wzT^T + bz.  MFMA, BM=64, BN=256 (2 col-blocks), BK=64.
// ---------------------------------------------------------------------------
__global__ __launch_bounds__(256) void k3_mfma(
    const float* __restrict__ yah, const _Float16* __restrict__ wzT,
    const float* __restrict__ bz, const float* __restrict__ x,
    float* __restrict__ out)
{
    __shared__ __align__(16) char lds_raw[40960];
    _Float16* Alds = (_Float16*)lds_raw;             // [64][64]
    _Float16* Blds = (_Float16*)(lds_raw + 8192);    // [256][64]

    const int t = threadIdx.x;
    const int m0 = blockIdx.x * 64;
    const int n0 = blockIdx.y * 256;
    const int lane = t & 63, w = t >> 6;
    const int arow = lane & 15, ak = (lane >> 4) * 8;

    f32x4 acc[4][4];
    #pragma unroll
    for (int i = 0; i < 4; ++i)
        #pragma unroll
        for (int j = 0; j < 4; ++j) acc[i][j] = (f32x4){0.f, 0.f, 0.f, 0.f};

    for (int k0 = 0; k0 < 512; k0 += 64) {
        __syncthreads();
        {   // stage A: h2-packed rows, pure copy. 64 rows x 32 floats
            const int r = t >> 2, c0 = (t & 3) * 8;   // float chunk
            const float4* src = (const float4*)(yah + (size_t)(m0 + r) * 256 + k0 / 2 + c0);
            float4* dst = (float4*)(Alds + r * 64 + c0 * 2);
            dst[0] = src[0]; dst[1] = src[1];
        }
        {   // stage B: 256 n-rows x 64 k f16.  8 lanes cover one 128B row.
            #pragma unroll
            for (int i = 0; i < 8; ++i) {
                int idx = t + i * 256;               // 0..2047
                int row = idx >> 3, ch = idx & 7;
                *(float4*)(Blds + row * 64 + ch * 8) =
                    *(const float4*)(wzT + (size_t)(n0 + row) * 512 + k0 + ch * 8);
            }
        }
        __syncthreads();

        #pragma unroll
        for (int kk = 0; kk < 2; ++kk) {
            h8 af[4], bf[4];
            #pragma unroll
            for (int rb = 0; rb < 4; ++rb)
                af[rb] = *(const h8*)(Alds + (rb * 16 + arow) * 64 + kk * 32 + ak);
            #pragma unroll
            for (int cf = 0; cf < 4; ++cf)
                bf[cf] = *(const h8*)(Blds + (w * 64 + cf * 16 + arow) * 64 + kk * 32 + ak);
            #pragma unroll
            for (int rb = 0; rb < 4; ++rb)
                #pragma unroll
                for (int cf = 0; cf < 4; ++cf)
                    acc[rb][cf] = __builtin_amdgcn_mfma_f32_16x16x32_f16(
                        af[rb], bf[cf], acc[rb][cf], 0, 0, 0);
        }
    }

    #pragma unroll
    for (int cf = 0; cf < 4; ++cf) {
        const int c = n0 + w * 64 + cf * 16 + arow;
        const float bv = bz[c];
        #pragma unroll
        for (int rb = 0; rb < 4; ++rb) {
            #pragma unroll
            for (int j = 0; j < 4; ++j) {
                int row = m0 + rb * 16 + (lane >> 4) * 4 + j;
                out[(size_t)row * 512 + c] =
                    acc[rb][cf][j] + bv + x[(size_t)row * 512 + c];
            }
        }
    }
}

extern "C" void kernel_launch(void* const* d_in, const int* in_sizes, int n_in,
                              void* d_out, int out_size, void* d_ws, size_t ws_size,
                              hipStream_t stream)
{
    (void)in_sizes; (void)n_in; (void)out_size; (void)ws_size;

    const float* x   = (const float*)d_in[0];
    const float* wg  = (const float*)d_in[1];
    const float* bg  = (const float*)d_in[2];
    const float* w1  = (const float*)d_in[3];
    const float* b1  = (const float*)d_in[4];
    const float* w2  = (const float*)d_in[5];
    const float* b2  = (const float*)d_in[6];
    const float* wzw = (const float*)d_in[7];
    const float* wzb = (const float*)d_in[8];
    const int* xlen  = (const int*)d_in[9];
    float* outp      = (float*)d_out;

    char* ws = (char*)d_ws;
    _Float16* wT   = (_Float16*)(ws);                       // 1 MiB [1024][512] f16
    _Float16* wzT  = (_Float16*)(ws + 1u * 1024 * 1024);    // 0.5 MiB [512][512] f16
    float* x1pw    = (float*)(ws +  2u * 1024 * 1024);      // 8 MiB [16384][128] h2
    float* x2tpw   = (float*)(ws + 10u * 1024 * 1024);      // 8 MiB [8][128][2048] h2
    float* xphw    = (float*)(ws + 18u * 1024 * 1024);      // 16 MiB [16384][256] h2
    float* yahw    = (float*)(ws + 34u * 1024 * 1024);      // 16 MiB [16384][256] h2

    // k0: pack weights (transposed, f16)
    hipLaunchKernelGGL(k0_tp, dim3(16, 16), dim3(256), 0, stream, wg,  wT,            512, 512);
    hipLaunchKernelGGL(k0_tp, dim3(8, 16),  dim3(256), 0, stream, w1,  wT + 512*512,  512, 256);
    hipLaunchKernelGGL(k0_tp, dim3(8, 16),  dim3(256), 0, stream, w2,  wT + 768*512,  512, 256);
    hipLaunchKernelGGL(k0_tp, dim3(16, 16), dim3(256), 0, stream, wzw, wzT,           512, 512);

    hipLaunchKernelGGL(k1_mfma, dim3(256, 4), dim3(256), 0, stream,
                       x, wT, bg, b1, b2, xphw, x1pw, x2tpw);
    hipLaunchKernelGGL(k2_attn, dim3(2048), dim3(256), 0, stream,
                       x1pw, x2tpw, xphw, xlen, yahw);
    hipLaunchKernelGGL(k3_mfma, dim3(256, 2), dim3(256), 0, stream,
                       yahw, wzT, wzb, x, outp);
}

// Round 9
// 350.198 us; speedup vs baseline: 1.2546x; 1.2546x over previous
//
#include <hip/hip_runtime.h>

// B=8, L=2048, D=512, H=512, E=256, K=30.  fp32 I/O, x_lengths int32.
// Identity: softmax -> key-mask -> renorm -> top-30 -> renorm ==
//   softmax over the 30 largest raw logits among valid keys (len >= 1024 >> 30).
// GEMMs (k1,k3): f16 MFMA.  Scores: v_dot2_f32_f16, key-split across 8 waves
// (panel read ONCE per block), u-packed (21-bit score | 11-bit reverse index)
// into an LDS score matrix; per-row top-30 extraction: one row per wave.

typedef _Float16 h2   __attribute__((ext_vector_type(2)));
typedef _Float16 h4   __attribute__((ext_vector_type(4)));
typedef _Float16 h8   __attribute__((ext_vector_type(8)));
typedef float    f32x4 __attribute__((ext_vector_type(4)));

__device__ __forceinline__ h2 as_h2(float f) {
    union { float f; h2 h; } u; u.f = f; return u.h;
}
__device__ __forceinline__ float packh2(float a, float b) {
    union { h2 h; float f; } u; u.h.x = (_Float16)a; u.h.y = (_Float16)b; return u.f;
}

// ---------------------------------------------------------------------------
// k0: transpose-pack fp32 [K][N] -> f16 [N][K].  32x32 tiles.
// ---------------------------------------------------------------------------
__global__ __launch_bounds__(256) void k0_tp(
    const float* __restrict__ src, _Float16* __restrict__ dst, int Kd, int Nd)
{
    __shared__ float tile[32][33];
    const int t = threadIdx.x;
    const int n0 = blockIdx.x * 32, k0 = blockIdx.y * 32;
    const int r = t >> 3, c = (t & 7) * 4;
    *(float4*)&tile[r][c] = *(const float4*)(src + (size_t)(k0 + r) * Nd + n0 + c);
    __syncthreads();
    h4 hv;
    hv.x = (_Float16)tile[c + 0][r];
    hv.y = (_Float16)tile[c + 1][r];
    hv.z = (_Float16)tile[c + 2][r];
    hv.w = (_Float16)tile[c + 3][r];
    *(h4*)(dst + (size_t)(n0 + r) * Kd + k0 + c) = hv;
}

// ---------------------------------------------------------------------------
// k1: MFMA projection GEMM.  BM=64 rows x BN=256 cols, BK=64, 4 waves.
// blockIdx.y = col-block: 0,1 -> x_prime (h2-packed xph), 2 -> x1 (x1p),
// 3 -> x2 (transposed packed x2tp via LDS tile).
// ---------------------------------------------------------------------------
__global__ __launch_bounds__(256) void k1_mfma(
    const float* __restrict__ x, const _Float16* __restrict__ wT,
    const float* __restrict__ bg, const float* __restrict__ b1,
    const float* __restrict__ b2,
    float* __restrict__ xph, float* __restrict__ x1p, float* __restrict__ x2tp)
{
    __shared__ __align__(16) char lds_raw[40960];
    _Float16* Alds = (_Float16*)lds_raw;             // [64][64] f16 = 8 KB
    _Float16* Blds = (_Float16*)(lds_raw + 8192);    // [256][64] f16 = 32 KB

    const int t = threadIdx.x;
    const int m0 = blockIdx.x * 64;
    const int cb = blockIdx.y;
    const int n0 = cb * 256;                         // row base in wT
    const int lane = t & 63, w = t >> 6;
    const int arow = lane & 15, ak = (lane >> 4) * 8;

    f32x4 acc[4][4];
    #pragma unroll
    for (int i = 0; i < 4; ++i)
        #pragma unroll
        for (int j = 0; j < 4; ++j) acc[i][j] = (f32x4){0.f, 0.f, 0.f, 0.f};

    for (int k0 = 0; k0 < 512; k0 += 64) {
        __syncthreads();
        {   // stage A: 64 rows x 64 k fp32 -> f16
            const int r = t >> 2, c0 = (t & 3) * 16;
            const float* src = x + (size_t)(m0 + r) * 512 + k0 + c0;
            #pragma unroll
            for (int hvi = 0; hvi < 2; ++hvi) {
                float4 u0 = *(const float4*)(src + hvi * 8);
                float4 u1 = *(const float4*)(src + hvi * 8 + 4);
                h8 hv;
                hv[0] = (_Float16)u0.x; hv[1] = (_Float16)u0.y;
                hv[2] = (_Float16)u0.z; hv[3] = (_Float16)u0.w;
                hv[4] = (_Float16)u1.x; hv[5] = (_Float16)u1.y;
                hv[6] = (_Float16)u1.z; hv[7] = (_Float16)u1.w;
                *(h8*)(Alds + r * 64 + c0 + hvi * 8) = hv;
            }
        }
        {   // stage B: 256 n-rows x 64 k f16.  8 lanes cover one 128B row.
            #pragma unroll
            for (int i = 0; i < 8; ++i) {
                int idx = t + i * 256;               // 0..2047
                int row = idx >> 3, ch = idx & 7;
                *(float4*)(Blds + row * 64 + ch * 8) =
                    *(const float4*)(wT + (size_t)(n0 + row) * 512 + k0 + ch * 8);
            }
        }
        __syncthreads();

        #pragma unroll
        for (int kk = 0; kk < 2; ++kk) {
            h8 af[4], bf[4];
            #pragma unroll
            for (int rb = 0; rb < 4; ++rb)
                af[rb] = *(const h8*)(Alds + (rb * 16 + arow) * 64 + kk * 32 + ak);
            #pragma unroll
            for (int cf = 0; cf < 4; ++cf)
                bf[cf] = *(const h8*)(Blds + (w * 64 + cf * 16 + arow) * 64 + kk * 32 + ak);
            #pragma unroll
            for (int rb = 0; rb < 4; ++rb)
                #pragma unroll
                for (int cf = 0; cf < 4; ++cf)
                    acc[rb][cf] = __builtin_amdgcn_mfma_f32_16x16x32_f16(
                        af[rb], bf[cf], acc[rb][cf], 0, 0, 0);
        }
    }

    const float* bias = (cb < 2) ? (bg + cb * 256) : (cb == 2 ? b1 : b2);

    if (cb < 3) {
        // pack e-pairs via lane shuffle; even lanes store 4B
        float* dst; int epbase; size_t rstr;
        if (cb < 2) { dst = xph; epbase = cb * 128; rstr = 256; }
        else        { dst = x1p; epbase = 0;        rstr = 128; }
        #pragma unroll
        for (int cf = 0; cf < 4; ++cf) {
            const int c = w * 64 + cf * 16 + arow;
            const float bv = bias[c];
            #pragma unroll
            for (int rb = 0; rb < 4; ++rb) {
                #pragma unroll
                for (int j = 0; j < 4; ++j) {
                    float v = acc[rb][cf][j] + bv;
                    float o = __shfl_xor(v, 1);
                    if ((lane & 1) == 0) {
                        int row = m0 + rb * 16 + (lane >> 4) * 4 + j;
                        dst[(size_t)row * rstr + epbase + (c >> 1)] = packh2(v, o);
                    }
                }
            }
        }
    } else {
        // x2: pack pairs -> LDS tile T[ep][key] (stride 68) -> coalesced store
        __syncthreads();                              // done with Alds/Blds
        float* T = (float*)lds_raw;                   // [128][68] floats = 34816 B
        #pragma unroll
        for (int cf = 0; cf < 4; ++cf) {
            const int c = w * 64 + cf * 16 + arow;
            const float bv = bias[c];
            #pragma unroll
            for (int rb = 0; rb < 4; ++rb) {
                #pragma unroll
                for (int j = 0; j < 4; ++j) {
                    float v = acc[rb][cf][j] + bv;
                    float o = __shfl_xor(v, 1);
                    if ((lane & 1) == 0)
                        T[(c >> 1) * 68 + rb * 16 + (lane >> 4) * 4 + j] = packh2(v, o);
                }
            }
        }
        __syncthreads();
        const int bb = m0 >> 11, j0 = m0 & 2047;
        #pragma unroll
        for (int g = 0; g < 8; ++g) {
            int idx4 = t + g * 256;                   // 0..2047
            int ep = idx4 >> 4, ko = (idx4 & 15) * 4;
            float4 vv = *(const float4*)(T + ep * 68 + ko);
            *(float4*)(x2tp + ((size_t)bb * 128 + ep) * 2048 + j0 + ko) = vv;
        }
    }
}

// ---------------------------------------------------------------------------
// k2: 512 threads (8 waves), 8 query rows per block.
// Phase A (key-split): wave w scores all 8 rows x keys [w*256, w*256+256);
//   one float4 x2tp load per lane per ep feeds 8 rows -> block reads the
//   1 MB panel ONCE.  Scores u-packed -> LDS scU[8][2048].
// Phase B (row-split): wave w extracts top-30 of row w from scU
//   (value-only wave-max, round-7 proven macro).
// Phase C: unpack, shared softmax weights, h2-packed gather of x_prime.
// ---------------------------------------------------------------------------
__global__ __launch_bounds__(512, 2) void k2_attn(
    const float* __restrict__ x1p, const float* __restrict__ x2tp,
    const float* __restrict__ xph, const int* __restrict__ xlen,
    float* __restrict__ yah)
{
    __shared__ unsigned scU[8][2048];             // 64 KB score matrix
    __shared__ float    x1sT[128][8];             // 4 KB  x1 transposed (h2 pairs)
    __shared__ unsigned tkp[8][30];
    __shared__ float    wvs[8][30];
    __shared__ int      tki[8][30];
    __shared__ float    vin[8];

    const int t  = threadIdx.x;
    const int b  = blockIdx.x >> 8;               // 256 row-blocks per batch
    const int i0 = (blockIdx.x & 255) * 8;
    const int len = xlen[b];

    {   // stage x1 (8 rows x 128 ep-pairs) transposed into LDS; 2 floats/thread
        const float* x1b = x1p + ((size_t)b * 2048 + i0) * 128;
        const int f = t * 2;                      // 0..1022, even
        const int row = f >> 7, ep = f & 127;
        float2 v = *(const float2*)(x1b + f);
        x1sT[ep + 0][row] = v.x;
        x1sT[ep + 1][row] = v.y;
    }
    __syncthreads();

    const int lane = t & 63, wid = t >> 6;        // 8 waves
    const int kb0 = wid * 256 + lane * 4;         // this lane's 4 keys

    // ---- phase A: scores, 8 rows x 4 keys per lane ----
    float acc[8][4];
    #pragma unroll
    for (int r = 0; r < 8; ++r)
        #pragma unroll
        for (int kk = 0; kk < 4; ++kk) acc[r][kk] = 0.f;

    const float* x2tb = x2tp + (size_t)b * 128 * 2048;
    for (int ep = 0; ep < 128; ++ep) {
        float4 kv = *(const float4*)(x2tb + (size_t)ep * 2048 + kb0);
        float4 xa = *(const float4*)&x1sT[ep][0];
        float4 xb = *(const float4*)&x1sT[ep][4];
        const h2 xr[8] = { as_h2(xa.x), as_h2(xa.y), as_h2(xa.z), as_h2(xa.w),
                           as_h2(xb.x), as_h2(xb.y), as_h2(xb.z), as_h2(xb.w) };
        const h2 kh[4] = { as_h2(kv.x), as_h2(kv.y), as_h2(kv.z), as_h2(kv.w) };
        #pragma unroll
        for (int r = 0; r < 8; ++r)
            #pragma unroll
            for (int kk = 0; kk < 4; ++kk)
                acc[r][kk] = __builtin_amdgcn_fdot2(xr[r], kh[kk], acc[r][kk], false);
    }

    // ---- u-pack + store to LDS score matrix ----
    #pragma unroll
    for (int r = 0; r < 8; ++r) {
        unsigned uu[4];
        #pragma unroll
        for (int kk = 0; kk < 4; ++kk) {
            const int j = kb0 + kk;
            const unsigned tag = (unsigned)(2047 - j);
            unsigned bb = __float_as_uint(acc[r][kk]);
            bb = bb ^ (0x80000000u | (unsigned)((int)bb >> 31));
            uu[kk] = (j < len) ? ((bb & 0xFFFFF800u) | tag) : 0u;
        }
        *(uint4*)&scU[r][kb0] = make_uint4(uu[0], uu[1], uu[2], uu[3]);
    }
    __syncthreads();

    // ---- phase B: top-30; wave w owns row w ----
    const int cbase = lane * 4;
    unsigned u0[32];
    #pragma unroll
    for (int c = 0; c < 8; ++c)
        *(uint4*)&u0[c * 4] = *(const uint4*)&scU[wid][cbase + c * 256];

    for (int it = 0; it < 30; ++it) {
        unsigned mx = 0u;
        #pragma unroll
        for (int q = 0; q < 32; ++q) mx = mx > u0[q] ? mx : u0[q];
        #pragma unroll
        for (int off = 32; off > 0; off >>= 1) {
            unsigned o = (unsigned)__shfl_xor((int)mx, off);
            mx = mx > o ? mx : o;
        }
        if (lane == 0) tkp[wid][it] = mx;
        #pragma unroll
        for (int q = 0; q < 32; ++q) u0[q] = (u0[q] == mx) ? 0u : u0[q];
    }
    __syncthreads();

    // ---- unpack + per-row softmax weights ----
    {
        const int r = t >> 6, k = t & 63;         // one wave per row
        if (k < 30) {
            unsigned u = tkp[r][k];
            unsigned m0 = tkp[r][0] & 0xFFFFF800u;
            unsigned ub = u & 0xFFFFF800u;
            unsigned bb0 = (m0 & 0x80000000u) ? (m0 ^ 0x80000000u) : ~m0;
            unsigned bbk = (ub & 0x80000000u) ? (ub ^ 0x80000000u) : ~ub;
            float s0 = __uint_as_float(bb0);
            float sk = __uint_as_float(bbk);
            wvs[r][k] = __expf(sk - s0);
            tki[r][k] = 2047 - (int)(u & 0x7FFu);
        }
    }
    __syncthreads();
    if (t < 8) {
        float s = 0.f;
        #pragma unroll
        for (int k = 0; k < 30; ++k) s += wvs[t][k];
        vin[t] = 1.f / s;
    }
    __syncthreads();

    // ---- phase C: gather of h2-packed x_prime; half-block per 4 rows ----
    const int g  = t >> 8;                        // 0..1 -> rows g*4..g*4+4
    const int hp = t & 255;                       // h2-pair index
    for (int r = g * 4; r < g * 4 + 4; ++r) {
        float y0 = 0.f, y1 = 0.f;
        #pragma unroll
        for (int k = 0; k < 30; ++k) {
            int j = tki[r][k];
            float wv = wvs[r][k];
            h2 u = as_h2(xph[((size_t)b * 2048 + j) * 256 + hp]);
            y0 = fmaf(wv, (float)u.x, y0);
            y1 = fmaf(wv, (float)u.y, y1);
        }
        const float inv = vin[r];
        yah[((size_t)b * 2048 + i0 + r) * 256 + hp] = packh2(y0 * inv, y1 * inv);
    }
}

// ---------------------------------------------------------------------------
// k3: out = x + yah @ wzT^T + bz.  MFMA, BM=64, BN=256 (2 col-blocks), BK=64.
// ---------------------------------------------------------------------------
__global__ __launch_bounds__(256) void k3_mfma(
    const float* __restrict__ yah, const _Float16* __restrict__ wzT,
    const float* __restrict__ bz, const float* __restrict__ x,
    float* __restrict__ out)
{
    __shared__ __align__(16) char lds_raw[40960];
    _Float16* Alds = (_Float16*)lds_raw;             // [64][64]
    _Float16* Blds = (_Float16*)(lds_raw + 8192);    // [256][64]

    const int t = threadIdx.x;
    const int m0 = blockIdx.x * 64;
    const int n0 = blockIdx.y * 256;
    const int lane = t & 63, w = t >> 6;
    const int arow = lane & 15, ak = (lane >> 4) * 8;

    f32x4 acc[4][4];
    #pragma unroll
    for (int i = 0; i < 4; ++i)
        #pragma unroll
        for (int j = 0; j < 4; ++j) acc[i][j] = (f32x4){0.f, 0.f, 0.f, 0.f};

    for (int k0 = 0; k0 < 512; k0 += 64) {
        __syncthreads();
        {   // stage A: h2-packed rows, pure copy. 64 rows x 32 floats
            const int r = t >> 2, c0 = (t & 3) * 8;   // float chunk
            const float4* src = (const float4*)(yah + (size_t)(m0 + r) * 256 + k0 / 2 + c0);
            float4* dst = (float4*)(Alds + r * 64 + c0 * 2);
            dst[0] = src[0]; dst[1] = src[1];
        }
        {   // stage B: 256 n-rows x 64 k f16.  8 lanes cover one 128B row.
            #pragma unroll
            for (int i = 0; i < 8; ++i) {
                int idx = t + i * 256;               // 0..2047
                int row = idx >> 3, ch = idx & 7;
                *(float4*)(Blds + row * 64 + ch * 8) =
                    *(const float4*)(wzT + (size_t)(n0 + row) * 512 + k0 + ch * 8);
            }
        }
        __syncthreads();

        #pragma unroll
        for (int kk = 0; kk < 2; ++kk) {
            h8 af[4], bf[4];
            #pragma unroll
            for (int rb = 0; rb < 4; ++rb)
                af[rb] = *(const h8*)(Alds + (rb * 16 + arow) * 64 + kk * 32 + ak);
            #pragma unroll
            for (int cf = 0; cf < 4; ++cf)
                bf[cf] = *(const h8*)(Blds + (w * 64 + cf * 16 + arow) * 64 + kk * 32 + ak);
            #pragma unroll
            for (int rb = 0; rb < 4; ++rb)
                #pragma unroll
                for (int cf = 0; cf < 4; ++cf)
                    acc[rb][cf] = __builtin_amdgcn_mfma_f32_16x16x32_f16(
                        af[rb], bf[cf], acc[rb][cf], 0, 0, 0);
        }
    }

    #pragma unroll
    for (int cf = 0; cf < 4; ++cf) {
        const int c = n0 + w * 64 + cf * 16 + arow;
        const float bv = bz[c];
        #pragma unroll
        for (int rb = 0; rb < 4; ++rb) {
            #pragma unroll
            for (int j = 0; j < 4; ++j) {
                int row = m0 + rb * 16 + (lane >> 4) * 4 + j;
                out[(size_t)row * 512 + c] =
                    acc[rb][cf][j] + bv + x[(size_t)row * 512 + c];
            }
        }
    }
}

extern "C" void kernel_launch(void* const* d_in, const int* in_sizes, int n_in,
                              void* d_out, int out_size, void* d_ws, size_t ws_size,
                              hipStream_t stream)
{
    (void)in_sizes; (void)n_in; (void)out_size; (void)ws_size;

    const float* x   = (const float*)d_in[0];
    const float* wg  = (const float*)d_in[1];
    const float* bg  = (const float*)d_in[2];
    const float* w1  = (const float*)d_in[3];
    const float* b1  = (const float*)d_in[4];
    const float* w2  = (const float*)d_in[5];
    const float* b2  = (const float*)d_in[6];
    const float* wzw = (const float*)d_in[7];
    const float* wzb = (const float*)d_in[8];
    const int* xlen  = (const int*)d_in[9];
    float* outp      = (float*)d_out;

    char* ws = (char*)d_ws;
    _Float16* wT   = (_Float16*)(ws);                       // 1 MiB [1024][512] f16
    _Float16* wzT  = (_Float16*)(ws + 1u * 1024 * 1024);    // 0.5 MiB [512][512] f16
    float* x1pw    = (float*)(ws +  2u * 1024 * 1024);      // 8 MiB [16384][128] h2
    float* x2tpw   = (float*)(ws + 10u * 1024 * 1024);      // 8 MiB [8][128][2048] h2
    float* xphw    = (float*)(ws + 18u * 1024 * 1024);      // 16 MiB [16384][256] h2
    float* yahw    = (float*)(ws + 34u * 1024 * 1024);      // 16 MiB [16384][256] h2

    // k0: pack weights (transposed, f16)
    hipLaunchKernelGGL(k0_tp, dim3(16, 16), dim3(256), 0, stream, wg,  wT,            512, 512);
    hipLaunchKernelGGL(k0_tp, dim3(8, 16),  dim3(256), 0, stream, w1,  wT + 512*512,  512, 256);
    hipLaunchKernelGGL(k0_tp, dim3(8, 16),  dim3(256), 0, stream, w2,  wT + 768*512,  512, 256);
    hipLaunchKernelGGL(k0_tp, dim3(16, 16), dim3(256), 0, stream, wzw, wzT,           512, 512);

    hipLaunchKernelGGL(k1_mfma, dim3(256, 4), dim3(256), 0, stream,
                       x, wT, bg, b1, b2, xphw, x1pw, x2tpw);
    hipLaunchKernelGGL(k2_attn, dim3(2048), dim3(512), 0, stream,
                       x1pw, x2tpw, xphw, xlen, yahw);
    hipLaunchKernelGGL(k3_mfma, dim3(256, 2), dim3(256), 0, stream,
                       yahw, wzT, wzb, x, outp);
}

// Round 10
// 317.447 us; speedup vs baseline: 1.3840x; 1.1032x over previous
//
#include <hip/hip_runtime.h>

// B=8, L=2048, D=512, H=512, E=256, K=30.  fp32 I/O, x_lengths int32.
// Identity: softmax -> key-mask -> renorm -> top-30 -> renorm ==
//   softmax over the 30 largest raw logits among valid keys (len >= 1024 >> 30).
// GEMMs (k1,k3): f16 MFMA.  k2 scores: f16 MFMA (8 rows padded to 16, wave owns
// a 256-key slice), u-packed (21-bit score | 11-bit reverse index) into an LDS
// score matrix; per-row top-30 extraction: one row per wave, value-only wave-max.

typedef _Float16 h2   __attribute__((ext_vector_type(2)));
typedef _Float16 h4   __attribute__((ext_vector_type(4)));
typedef _Float16 h8   __attribute__((ext_vector_type(8)));
typedef float    f32x4 __attribute__((ext_vector_type(4)));

__device__ __forceinline__ h2 as_h2(float f) {
    union { float f; h2 h; } u; u.f = f; return u.h;
}
__device__ __forceinline__ float packh2(float a, float b) {
    union { h2 h; float f; } u; u.h.x = (_Float16)a; u.h.y = (_Float16)b; return u.f;
}
__device__ __forceinline__ h8 mk_h8(float a, float b, float c, float d) {
    union { float f[4]; h8 h; } u;
    u.f[0] = a; u.f[1] = b; u.f[2] = c; u.f[3] = d; return u.h;
}

// ---------------------------------------------------------------------------
// k0: transpose-pack fp32 [K][N] -> f16 [N][K].  32x32 tiles.
// ---------------------------------------------------------------------------
__global__ __launch_bounds__(256) void k0_tp(
    const float* __restrict__ src, _Float16* __restrict__ dst, int Kd, int Nd)
{
    __shared__ float tile[32][33];
    const int t = threadIdx.x;
    const int n0 = blockIdx.x * 32, k0 = blockIdx.y * 32;
    const int r = t >> 3, c = (t & 7) * 4;
    *(float4*)&tile[r][c] = *(const float4*)(src + (size_t)(k0 + r) * Nd + n0 + c);
    __syncthreads();
    h4 hv;
    hv.x = (_Float16)tile[c + 0][r];
    hv.y = (_Float16)tile[c + 1][r];
    hv.z = (_Float16)tile[c + 2][r];
    hv.w = (_Float16)tile[c + 3][r];
    *(h4*)(dst + (size_t)(n0 + r) * Kd + k0 + c) = hv;
}

// ---------------------------------------------------------------------------
// k1: MFMA projection GEMM.  BM=64 rows x BN=256 cols, BK=64, 4 waves.
// blockIdx.y = col-block: 0,1 -> x_prime (h2-packed xph), 2 -> x1 (x1p),
// 3 -> x2 (transposed packed x2tp via LDS tile).
// ---------------------------------------------------------------------------
__global__ __launch_bounds__(256) void k1_mfma(
    const float* __restrict__ x, const _Float16* __restrict__ wT,
    const float* __restrict__ bg, const float* __restrict__ b1,
    const float* __restrict__ b2,
    float* __restrict__ xph, float* __restrict__ x1p, float* __restrict__ x2tp)
{
    __shared__ __align__(16) char lds_raw[40960];
    _Float16* Alds = (_Float16*)lds_raw;             // [64][64] f16 = 8 KB
    _Float16* Blds = (_Float16*)(lds_raw + 8192);    // [256][64] f16 = 32 KB

    const int t = threadIdx.x;
    const int m0 = blockIdx.x * 64;
    const int cb = blockIdx.y;
    const int n0 = cb * 256;                         // row base in wT
    const int lane = t & 63, w = t >> 6;
    const int arow = lane & 15, ak = (lane >> 4) * 8;

    f32x4 acc[4][4];
    #pragma unroll
    for (int i = 0; i < 4; ++i)
        #pragma unroll
        for (int j = 0; j < 4; ++j) acc[i][j] = (f32x4){0.f, 0.f, 0.f, 0.f};

    for (int k0 = 0; k0 < 512; k0 += 64) {
        __syncthreads();
        {   // stage A: 64 rows x 64 k fp32 -> f16
            const int r = t >> 2, c0 = (t & 3) * 16;
            const float* src = x + (size_t)(m0 + r) * 512 + k0 + c0;
            #pragma unroll
            for (int hvi = 0; hvi < 2; ++hvi) {
                float4 u0 = *(const float4*)(src + hvi * 8);
                float4 u1 = *(const float4*)(src + hvi * 8 + 4);
                h8 hv;
                hv[0] = (_Float16)u0.x; hv[1] = (_Float16)u0.y;
                hv[2] = (_Float16)u0.z; hv[3] = (_Float16)u0.w;
                hv[4] = (_Float16)u1.x; hv[5] = (_Float16)u1.y;
                hv[6] = (_Float16)u1.z; hv[7] = (_Float16)u1.w;
                *(h8*)(Alds + r * 64 + c0 + hvi * 8) = hv;
            }
        }
        {   // stage B: 256 n-rows x 64 k f16.  8 lanes cover one 128B row.
            #pragma unroll
            for (int i = 0; i < 8; ++i) {
                int idx = t + i * 256;               // 0..2047
                int row = idx >> 3, ch = idx & 7;
                *(float4*)(Blds + row * 64 + ch * 8) =
                    *(const float4*)(wT + (size_t)(n0 + row) * 512 + k0 + ch * 8);
            }
        }
        __syncthreads();

        #pragma unroll
        for (int kk = 0; kk < 2; ++kk) {
            h8 af[4], bf[4];
            #pragma unroll
            for (int rb = 0; rb < 4; ++rb)
                af[rb] = *(const h8*)(Alds + (rb * 16 + arow) * 64 + kk * 32 + ak);
            #pragma unroll
            for (int cf = 0; cf < 4; ++cf)
                bf[cf] = *(const h8*)(Blds + (w * 64 + cf * 16 + arow) * 64 + kk * 32 + ak);
            #pragma unroll
            for (int rb = 0; rb < 4; ++rb)
                #pragma unroll
                for (int cf = 0; cf < 4; ++cf)
                    acc[rb][cf] = __builtin_amdgcn_mfma_f32_16x16x32_f16(
                        af[rb], bf[cf], acc[rb][cf], 0, 0, 0);
        }
    }

    const float* bias = (cb < 2) ? (bg + cb * 256) : (cb == 2 ? b1 : b2);

    if (cb < 3) {
        // pack e-pairs via lane shuffle; even lanes store 4B
        float* dst; int epbase; size_t rstr;
        if (cb < 2) { dst = xph; epbase = cb * 128; rstr = 256; }
        else        { dst = x1p; epbase = 0;        rstr = 128; }
        #pragma unroll
        for (int cf = 0; cf < 4; ++cf) {
            const int c = w * 64 + cf * 16 + arow;
            const float bv = bias[c];
            #pragma unroll
            for (int rb = 0; rb < 4; ++rb) {
                #pragma unroll
                for (int j = 0; j < 4; ++j) {
                    float v = acc[rb][cf][j] + bv;
                    float o = __shfl_xor(v, 1);
                    if ((lane & 1) == 0) {
                        int row = m0 + rb * 16 + (lane >> 4) * 4 + j;
                        dst[(size_t)row * rstr + epbase + (c >> 1)] = packh2(v, o);
                    }
                }
            }
        }
    } else {
        // x2: pack pairs -> LDS tile T[ep][key] (stride 68) -> coalesced store
        __syncthreads();                              // done with Alds/Blds
        float* T = (float*)lds_raw;                   // [128][68] floats = 34816 B
        #pragma unroll
        for (int cf = 0; cf < 4; ++cf) {
            const int c = w * 64 + cf * 16 + arow;
            const float bv = bias[c];
            #pragma unroll
            for (int rb = 0; rb < 4; ++rb) {
                #pragma unroll
                for (int j = 0; j < 4; ++j) {
                    float v = acc[rb][cf][j] + bv;
                    float o = __shfl_xor(v, 1);
                    if ((lane & 1) == 0)
                        T[(c >> 1) * 68 + rb * 16 + (lane >> 4) * 4 + j] = packh2(v, o);
                }
            }
        }
        __syncthreads();
        const int bb = m0 >> 11, j0 = m0 & 2047;
        #pragma unroll
        for (int g = 0; g < 8; ++g) {
            int idx4 = t + g * 256;                   // 0..2047
            int ep = idx4 >> 4, ko = (idx4 & 15) * 4;
            float4 vv = *(const float4*)(T + ep * 68 + ko);
            *(float4*)(x2tp + ((size_t)bb * 128 + ep) * 2048 + j0 + ko) = vv;
        }
    }
}

// ---------------------------------------------------------------------------
// k2: 512 threads (8 waves), 8 query rows per block.
// Phase A (MFMA): A = x1 rows i0..i0+7 padded to 16 by row duplication
//   (lanes with lane&15 >= 8 re-read row&7; their C rows are duplicates and
//   are not stored).  Wave w computes keys [w*256, w*256+256) as 16 tiles x
//   8 k-steps of mfma_f32_16x16x32_f16.  B fragments: 4 strided dwords from
//   x2tp ([ep][key] h2).  Scores u-packed -> LDS scU[8][2048].
// Phase B: wave w extracts top-30 of row w (value-only wave-max, proven).
// Phase C: unpack, shared softmax weights, h2-packed gather of x_prime.
// ---------------------------------------------------------------------------
__global__ __launch_bounds__(512, 4) void k2_attn(
    const float* __restrict__ x1p, const float* __restrict__ x2tp,
    const float* __restrict__ xph, const int* __restrict__ xlen,
    float* __restrict__ yah)
{
    __shared__ unsigned scU[8][2048];             // 64 KB score matrix
    __shared__ unsigned tkp[8][30];
    __shared__ float    wvs[8][30];
    __shared__ int      tki[8][30];
    __shared__ float    vin[8];

    const int t  = threadIdx.x;
    const int b  = blockIdx.x >> 8;               // 256 row-blocks per batch
    const int i0 = (blockIdx.x & 255) * 8;
    const int len = xlen[b];
    const int lane = t & 63, wid = t >> 6;        // 8 waves

    // ---- phase A: MFMA scores ----
    h8 afr[8];
    {   // A fragments: row = lane&15 (dup to row&7), k = (lane>>4)*8 + ks*32
        const int ar = (lane & 15) & 7;
        const float* x1row = x1p + ((size_t)b * 2048 + i0 + ar) * 128 + (lane >> 4) * 4;
        #pragma unroll
        for (int ks = 0; ks < 8; ++ks)
            afr[ks] = *(const h8*)(x1row + ks * 16);
    }

    const float* x2tb = x2tp + (size_t)b * 128 * 2048;
    const int jcol  = lane & 15;
    const int epb   = (lane >> 4) * 4;            // ep base within k-step
    const int rbase = (lane >> 4) * 4;            // C row base

    for (int nt = 0; nt < 16; ++nt) {
        const int j = wid * 256 + nt * 16 + jcol;
        f32x4 acc = (f32x4){0.f, 0.f, 0.f, 0.f};
        #pragma unroll
        for (int ks = 0; ks < 8; ++ks) {
            const float* p = x2tb + (size_t)(ks * 16 + epb) * 2048 + j;
            h8 bfr = mk_h8(p[0], p[2048], p[4096], p[6144]);
            acc = __builtin_amdgcn_mfma_f32_16x16x32_f16(afr[ks], bfr, acc, 0, 0, 0);
        }
        if (rbase < 8) {                          // rows 8-15 are duplicates
            const unsigned tag = (unsigned)(2047 - j);
            const bool valid = (j < len);
            #pragma unroll
            for (int jj = 0; jj < 4; ++jj) {
                unsigned bb = __float_as_uint(acc[jj]);
                bb = bb ^ (0x80000000u | (unsigned)((int)bb >> 31));
                scU[rbase + jj][j] = valid ? ((bb & 0xFFFFF800u) | tag) : 0u;
            }
        }
    }
    __syncthreads();

    // ---- phase B: top-30; wave w owns row w ----
    const int cbase = lane * 4;
    unsigned u0[32];
    #pragma unroll
    for (int c = 0; c < 8; ++c)
        *(uint4*)&u0[c * 4] = *(const uint4*)&scU[wid][cbase + c * 256];

    for (int it = 0; it < 30; ++it) {
        unsigned mx = 0u;
        #pragma unroll
        for (int q = 0; q < 32; ++q) mx = mx > u0[q] ? mx : u0[q];
        #pragma unroll
        for (int off = 32; off > 0; off >>= 1) {
            unsigned o = (unsigned)__shfl_xor((int)mx, off);
            mx = mx > o ? mx : o;
        }
        if (lane == 0) tkp[wid][it] = mx;
        #pragma unroll
        for (int q = 0; q < 32; ++q) u0[q] = (u0[q] == mx) ? 0u : u0[q];
    }
    __syncthreads();

    // ---- unpack + per-row softmax weights ----
    {
        const int r = t >> 6, k = t & 63;         // one wave per row
        if (k < 30) {
            unsigned u = tkp[r][k];
            unsigned m0 = tkp[r][0] & 0xFFFFF800u;
            unsigned ub = u & 0xFFFFF800u;
            unsigned bb0 = (m0 & 0x80000000u) ? (m0 ^ 0x80000000u) : ~m0;
            unsigned bbk = (ub & 0x80000000u) ? (ub ^ 0x80000000u) : ~ub;
            float s0 = __uint_as_float(bb0);
            float sk = __uint_as_float(bbk);
            wvs[r][k] = __expf(sk - s0);
            tki[r][k] = 2047 - (int)(u & 0x7FFu);
        }
    }
    __syncthreads();
    if (t < 8) {
        float s = 0.f;
        #pragma unroll
        for (int k = 0; k < 30; ++k) s += wvs[t][k];
        vin[t] = 1.f / s;
    }
    __syncthreads();

    // ---- phase C: gather of h2-packed x_prime; half-block per 4 rows ----
    const int g  = t >> 8;                        // 0..1 -> rows g*4..g*4+4
    const int hp = t & 255;                       // h2-pair index
    for (int r = g * 4; r < g * 4 + 4; ++r) {
        float y0 = 0.f, y1 = 0.f;
        #pragma unroll
        for (int k = 0; k < 30; ++k) {
            int j = tki[r][k];
            float wv = wvs[r][k];
            h2 u = as_h2(xph[((size_t)b * 2048 + j) * 256 + hp]);
            y0 = fmaf(wv, (float)u.x, y0);
            y1 = fmaf(wv, (float)u.y, y1);
        }
        const float inv = vin[r];
        yah[((size_t)b * 2048 + i0 + r) * 256 + hp] = packh2(y0 * inv, y1 * inv);
    }
}

// ---------------------------------------------------------------------------
// k3: out = x + yah @ wzT^T + bz.  MFMA, BM=64, BN=256 (2 col-blocks), BK=64.
// ---------------------------------------------------------------------------
__global__ __launch_bounds__(256) void k3_mfma(
    const float* __restrict__ yah, const _Float16* __restrict__ wzT,
    const float* __restrict__ bz, const float* __restrict__ x,
    float* __restrict__ out)
{
    __shared__ __align__(16) char lds_raw[40960];
    _Float16* Alds = (_Float16*)lds_raw;             // [64][64]
    _Float16* Blds = (_Float16*)(lds_raw + 8192);    // [256][64]

    const int t = threadIdx.x;
    const int m0 = blockIdx.x * 64;
    const int n0 = blockIdx.y * 256;
    const int lane = t & 63, w = t >> 6;
    const int arow = lane & 15, ak = (lane >> 4) * 8;

    f32x4 acc[4][4];
    #pragma unroll
    for (int i = 0; i < 4; ++i)
        #pragma unroll
        for (int j = 0; j < 4; ++j) acc[i][j] = (f32x4){0.f, 0.f, 0.f, 0.f};

    for (int k0 = 0; k0 < 512; k0 += 64) {
        __syncthreads();
        {   // stage A: h2-packed rows, pure copy. 64 rows x 32 floats
            const int r = t >> 2, c0 = (t & 3) * 8;   // float chunk
            const float4* src = (const float4*)(yah + (size_t)(m0 + r) * 256 + k0 / 2 + c0);
            float4* dst = (float4*)(Alds + r * 64 + c0 * 2);
            dst[0] = src[0]; dst[1] = src[1];
        }
        {   // stage B: 256 n-rows x 64 k f16.  8 lanes cover one 128B row.
            #pragma unroll
            for (int i = 0; i < 8; ++i) {
                int idx = t + i * 256;               // 0..2047
                int row = idx >> 3, ch = idx & 7;
                *(float4*)(Blds + row * 64 + ch * 8) =
                    *(const float4*)(wzT + (size_t)(n0 + row) * 512 + k0 + ch * 8);
            }
        }
        __syncthreads();

        #pragma unroll
        for (int kk = 0; kk < 2; ++kk) {
            h8 af[4], bf[4];
            #pragma unroll
            for (int rb = 0; rb < 4; ++rb)
                af[rb] = *(const h8*)(Alds + (rb * 16 + arow) * 64 + kk * 32 + ak);
            #pragma unroll
            for (int cf = 0; cf < 4; ++cf)
                bf[cf] = *(const h8*)(Blds + (w * 64 + cf * 16 + arow) * 64 + kk * 32 + ak);
            #pragma unroll
            for (int rb = 0; rb < 4; ++rb)
                #pragma unroll
                for (int cf = 0; cf < 4; ++cf)
                    acc[rb][cf] = __builtin_amdgcn_mfma_f32_16x16x32_f16(
                        af[rb], bf[cf], acc[rb][cf], 0, 0, 0);
        }
    }

    #pragma unroll
    for (int cf = 0; cf < 4; ++cf) {
        const int c = n0 + w * 64 + cf * 16 + arow;
        const float bv = bz[c];
        #pragma unroll
        for (int rb = 0; rb < 4; ++rb) {
            #pragma unroll
            for (int j = 0; j < 4; ++j) {
                int row = m0 + rb * 16 + (lane >> 4) * 4 + j;
                out[(size_t)row * 512 + c] =
                    acc[rb][cf][j] + bv + x[(size_t)row * 512 + c];
            }
        }
    }
}

extern "C" void kernel_launch(void* const* d_in, const int* in_sizes, int n_in,
                              void* d_out, int out_size, void* d_ws, size_t ws_size,
                              hipStream_t stream)
{
    (void)in_sizes; (void)n_in; (void)out_size; (void)ws_size;

    const float* x   = (const float*)d_in[0];
    const float* wg  = (const float*)d_in[1];
    const float* bg  = (const float*)d_in[2];
    const float* w1  = (const float*)d_in[3];
    const float* b1  = (const float*)d_in[4];
    const float* w2  = (const float*)d_in[5];
    const float* b2  = (const float*)d_in[6];
    const float* wzw = (const float*)d_in[7];
    const float* wzb = (const float*)d_in[8];
    const int* xlen  = (const int*)d_in[9];
    float* outp      = (float*)d_out;

    char* ws = (char*)d_ws;
    _Float16* wT   = (_Float16*)(ws);                       // 1 MiB [1024][512] f16
    _Float16* wzT  = (_Float16*)(ws + 1u * 1024 * 1024);    // 0.5 MiB [512][512] f16
    float* x1pw    = (float*)(ws +  2u * 1024 * 1024);      // 8 MiB [16384][128] h2
    float* x2tpw   = (float*)(ws + 10u * 1024 * 1024);      // 8 MiB [8][128][2048] h2
    float* xphw    = (float*)(ws + 18u * 1024 * 1024);      // 16 MiB [16384][256] h2
    float* yahw    = (float*)(ws + 34u * 1024 * 1024);      // 16 MiB [16384][256] h2

    // k0: pack weights (transposed, f16)
    hipLaunchKernelGGL(k0_tp, dim3(16, 16), dim3(256), 0, stream, wg,  wT,            512, 512);
    hipLaunchKernelGGL(k0_tp, dim3(8, 16),  dim3(256), 0, stream, w1,  wT + 512*512,  512, 256);
    hipLaunchKernelGGL(k0_tp, dim3(8, 16),  dim3(256), 0, stream, w2,  wT + 768*512,  512, 256);
    hipLaunchKernelGGL(k0_tp, dim3(16, 16), dim3(256), 0, stream, wzw, wzT,           512, 512);

    hipLaunchKernelGGL(k1_mfma, dim3(256, 4), dim3(256), 0, stream,
                       x, wT, bg, b1, b2, xphw, x1pw, x2tpw);
    hipLaunchKernelGGL(k2_attn, dim3(2048), dim3(512), 0, stream,
                       x1pw, x2tpw, xphw, xlen, yahw);
    hipLaunchKernelGGL(k3_mfma, dim3(256, 2), dim3(256), 0, stream,
                       yahw, wzT, wzb, x, outp);
}